// Round 2
// baseline (101.335 us; speedup 1.0000x reference)
//
#include <hip/hip_runtime.h>
#include <cstddef>

#define RR 80
#define NVIEW 4
#define CH 32
#define IH 64
#define IW 64
#define NPIX (IH*IW)
#define NVOX (RR*RR*RR)   // 512000

// G (f16) layout: [v][y][x][g(4)][8] — one pixel = 32 ch = 64 B = 1 cache line.
// b1 is pre-folded into G (bilinear weights sum to 1, so bilerp(G+b1)=bilerp(G)+b1).
#define PIX_H   32              // halves per pixel
#define VIEW_H  (NPIX*PIX_H)    // halves per view

typedef _Float16 half2_t  __attribute__((ext_vector_type(2)));
typedef _Float16 half4_t  __attribute__((ext_vector_type(4)));
typedef _Float16 half8_t  __attribute__((ext_vector_type(8)));
typedef float    float4_t __attribute__((ext_vector_type(4)));

union i2h2 { int i; half2_t h; };

// ---------------------------------------------------------------------------
// G[v][yx][g][e] = b1[8g+e] + sum_ic feats[v][ic][yx] * W1[ic][8g+e]
// 2 threads per pixel (16 out-ch each), 32 B contiguous stores -> coalesced.
// ---------------------------------------------------------------------------
__global__ __launch_bounds__(256) void g_precompute(
    const float* __restrict__ feats, const float* __restrict__ W1,
    const float* __restrict__ b1, _Float16* __restrict__ G)
{
    int tid = blockIdx.x*256 + threadIdx.x;      // 0..32767
    int p   = tid >> 1;                          // pixel 0..16383 (v*4096+yx)
    int hg  = tid & 1;                           // which 16-ch half
    __shared__ float sW1[CH*CH];
    __shared__ float sb1[CH];
    for (int t = threadIdx.x; t < CH*CH; t += 256) sW1[t] = W1[t];
    if (threadIdx.x < CH) sb1[threadIdx.x] = b1[threadIdx.x];
    __syncthreads();
    int v  = p >> 12;
    int yx = p & 4095;
    const float* fb = feats + ((size_t)v*CH)*NPIX + yx;
    float acc[16];
    #pragma unroll
    for (int e=0;e<16;++e) acc[e] = sb1[hg*16+e];
    #pragma unroll
    for (int ic=0; ic<CH; ++ic) {
        float fv = fb[(size_t)ic*NPIX];
        #pragma unroll
        for (int e=0;e<16;++e) acc[e] = fmaf(fv, sW1[ic*CH + hg*16 + e], acc[e]);
    }
    half8_t o0, o1;
    #pragma unroll
    for (int e=0;e<8;++e) { o0[e] = (_Float16)acc[e]; o1[e] = (_Float16)acc[8+e]; }
    _Float16* dst = G + (size_t)p*PIX_H + (size_t)hg*16;
    *(half8_t*)(dst)   = o0;
    *(half8_t*)(dst+8) = o1;
}

// ---------------------------------------------------------------------------
// Main: zero-LDS transposed MFMA MLP, deduplicated projection (64 lanes each
// project their OWN voxel once; packed results redistributed via ds_bpermute).
// NEW this round:
//  - depth-2 software pipeline over the view loop: gathers for view v+1 are
//    issued before view v is consumed, hiding L1/L2 gather latency.
//  - pixel-major G layout: one pixel's 32 ch = one 64B line; every line a
//    wave's gather touches is fully consumed (4 quads x 16B).
//  - b1 folded into G (saves the +b1h pk-adds and shortens the h1 chain).
// Clamp-based bounds unchanged; invalid lanes get addr 0 and weight 0.
// ---------------------------------------------------------------------------
__global__ __launch_bounds__(256) void dgfv_main(
    const _Float16* __restrict__ G,   // [NVIEW][IH][IW][4][8]
    const float* __restrict__ poses,
    const float* __restrict__ W2, const float* __restrict__ b2,
    const float* __restrict__ W3, const float* __restrict__ b3,
    float* __restrict__ out)
{
    const int wid  = threadIdx.x >> 6;
    const int lane = threadIdx.x & 63;
    const int lq   = lane >> 4;
    const int lc   = lane & 15;
    const int vown  = blockIdx.x*256 + wid*64 + lane;  // producer voxel
    const int vbase = blockIdx.x*256 + wid*64 + lc;    // consumer voxel: vbase+16p

    // ---- wave-resident fragments ----
    half8_t w2a;   // A-frag of W2^T: A[m=lc][k=lq*8+j] = W2[k][m]
    #pragma unroll
    for (int j=0;j<8;++j) w2a[j] = (_Float16)W2[(lq*8+j)*16 + lc];
    half4_t w3a;   // A-frag of W3^T, rows 8..15 duplicate 0..7
    #pragma unroll
    for (int j=0;j<4;++j) w3a[j] = (_Float16)W3[(lq*4+j)*8 + (lc&7)];
    float4_t c1init, c2init;
    #pragma unroll
    for (int r=0;r<4;++r) {
        c1init[r] = b2[lq*4+r];
        c2init[r] = b3[(lq*4+r)&7];
    }

    // ---- producer: project OWN voxel for all views (once) ----
    const float step = 2.0f/(float)(RR-1);
    int i  = vown % RR;
    int t  = vown / RR;
    int j_ = t % RR;
    int k_ = t / RR;
    float x = fmaf((float)i,  step, -1.0f);
    float y = fmaf((float)j_, step, -1.0f);
    float z = fmaf((float)k_, step, -1.0f);

    int wpa[NVIEW];   // packed f16 {w00, w10}
    int wpb[NVIEW];   // packed f16 {w01, w11}
    int adm[NVIEW];   // pixel offset in halves | valid<<31  (0 if invalid)
    #pragma unroll
    for (int v=0; v<NVIEW; ++v) {
        const float* P = poses + v*16;           // uniform -> scalar
        float px = fmaf(P[0],x, fmaf(P[1],y, fmaf(P[2], z, P[3])));
        float py = fmaf(P[4],x, fmaf(P[5],y, fmaf(P[6], z, P[7])));
        float pz = fmaf(P[8],x, fmaf(P[9],y, fmaf(P[10],z, P[11])));
        float r0 = __builtin_amdgcn_rcpf(pz);
        r0 = r0*(2.0f - pz*r0);                  // 1 Newton step
        float u  = px*r0;
        float w  = py*r0;

        bool ok = (pz > 0.f) && (u >= 0.f) && (u <= (float)(IW-1))
                             && (w >= 0.f) && (w <= (float)(IH-1));

        float uc = fminf(fmaxf(u, 0.f), (float)(IW-1));
        float wc = fminf(fmaxf(w, 0.f), (float)(IH-1));
        float fx0 = floorf(uc), fy0 = floorf(wc);
        float tx = uc - fx0, ty = wc - fy0;
        int x0 = (int)fx0, y0 = (int)fy0;
        float wx0 = 1.f - tx, wy0 = 1.f - ty;

        i2h2 pa, pb;
        pa.h.x = (_Float16)(wx0*wy0);  pa.h.y = (_Float16)(tx*wy0);
        pb.h.x = (_Float16)(wx0*ty);   pb.h.y = (_Float16)(tx*ty);
        wpa[v] = pa.i;
        wpb[v] = pb.i;
        unsigned paddr = (unsigned)((y0*IW + x0)*PIX_H);
        adm[v] = ok ? (int)(paddr | 0x80000000u) : 0;
    }

    const _Float16* Gq = G + (size_t)lq*8;   // quad's channel-group slice

#define GATHER(vv, Av, Bv, Cv, Dv)                                         \
    do {                                                                   \
        const _Float16* _bp = Gq + (size_t)(vv)*VIEW_H                     \
                                 + (size_t)(rm[vv] & 0x7FFFFFFF);          \
        Av = *(const half8_t*)(_bp);                                       \
        Bv = *(const half8_t*)(_bp + PIX_H);            /* x1 */           \
        Cv = *(const half8_t*)(_bp + IW*PIX_H);         /* y1 */           \
        Dv = *(const half8_t*)(_bp + IW*PIX_H + PIX_H);                    \
    } while (0)

#define COMPUTE(vv, Av, Bv, Cv, Dv)                                        \
    do {                                                                   \
        i2h2 _ua, _ub; _ua.i = ra[vv]; _ub.i = rb[vv];                     \
        half8_t _h1 = Av*_ua.h.x + Bv*_ua.h.y + Cv*_ub.h.x + Dv*_ub.h.y;   \
        _h1 = __builtin_elementwise_max(_h1, (half8_t)(_Float16)0.f);      \
        float4_t _d1 = __builtin_amdgcn_mfma_f32_16x16x32_f16(w2a, _h1, c1init, 0,0,0); \
        half4_t _h2;                                                       \
        _h2[0] = (_Float16)fmaxf(_d1[0], 0.f);                             \
        _h2[1] = (_Float16)fmaxf(_d1[1], 0.f);                             \
        _h2[2] = (_Float16)fmaxf(_d1[2], 0.f);                             \
        _h2[3] = (_Float16)fmaxf(_d1[3], 0.f);                             \
        float4_t _d2 = __builtin_amdgcn_mfma_f32_16x16x16f16(w3a, _h2, c2init, 0,0,0); \
        const bool _ok = (rm[vv] < 0);                                     \
        _Pragma("unroll")                                                  \
        for (int _r=0;_r<4;++_r) {                                         \
            float _h3 = _d2[_r];                                           \
            float _hm = _ok ? _h3 : 0.f;                                   \
            accA[_r] += _hm;                                               \
            accB[_r]  = fmaf(_hm, _h3, accB[_r]);                          \
        }                                                                  \
        accM += _ok ? 1.f : 0.f;                                           \
    } while (0)

    #pragma unroll
    for (int p=0; p<4; ++p) {
        const int vx   = vbase + 16*p;
        const int srcb = (lc + 16*p) << 2;   // source lane (bytes) for bpermute

        // redistribute this pass's 16-voxel projection set (addr first so
        // GATHER(0) only waits on the first lgkm group)
        int rm[NVIEW], ra[NVIEW], rb[NVIEW];
        #pragma unroll
        for (int v=0; v<NVIEW; ++v) rm[v] = __builtin_amdgcn_ds_bpermute(srcb, adm[v]);
        #pragma unroll
        for (int v=0; v<NVIEW; ++v) ra[v] = __builtin_amdgcn_ds_bpermute(srcb, wpa[v]);
        #pragma unroll
        for (int v=0; v<NVIEW; ++v) rb[v] = __builtin_amdgcn_ds_bpermute(srcb, wpb[v]);

        float accA[4], accB[4], accM = 0.f;
        #pragma unroll
        for (int r=0;r<4;++r) { accA[r]=0.f; accB[r]=0.f; }

        // depth-2 software pipeline over views: gathers for v+1 in flight
        // while view v is consumed
        half8_t A0,B0,C0,D0, A1,B1,C1,D1, A2,B2,C2,D2, A3,B3,C3,D3;
        GATHER(0, A0,B0,C0,D0);
        GATHER(1, A1,B1,C1,D1);
        COMPUTE(0, A0,B0,C0,D0);
        GATHER(2, A2,B2,C2,D2);
        COMPUTE(1, A1,B1,C1,D1);
        GATHER(3, A3,B3,C3,D3);
        COMPUTE(2, A2,B2,C2,D2);
        COMPUTE(3, A3,B3,C3,D3);

        // per-pass epilogue: quads 0,1 -> mean, quads 2,3 -> var
        float S   = accM + 1e-8f;
        float inv = 1.f/S;
        float sw  = accM*inv;
        #pragma unroll
        for (int r=0;r<4;++r) {
            float mean = accA[r]*inv;
            float var  = fmaf(-mean*mean, (2.f - sw), accB[r]*inv);
            float val  = (lq < 2) ? mean : var;
            int   cch  = 4*lq + r;
            out[(size_t)cch*NVOX + vx] = val;
        }
    }
#undef GATHER
#undef COMPUTE
}

extern "C" void kernel_launch(void* const* d_in, const int* in_sizes, int n_in,
                              void* d_out, int out_size, void* d_ws, size_t ws_size,
                              hipStream_t stream)
{
    const float* feats = (const float*)d_in[0];
    const float* poses = (const float*)d_in[1];
    const float* W1    = (const float*)d_in[2];
    const float* b1    = (const float*)d_in[3];
    const float* W2    = (const float*)d_in[4];
    const float* b2    = (const float*)d_in[5];
    const float* W3    = (const float*)d_in[6];
    const float* b3    = (const float*)d_in[7];
    float* out = (float*)d_out;

    _Float16* G = (_Float16*)d_ws;   // 1 MB
    g_precompute<<<128, 256, 0, stream>>>(feats, W1, b1, G);
    dgfv_main<<<NVOX/256, 256, 0, stream>>>(G, poses, W2, b2, W3, b3, out);
}

// Round 3
// 100.536 us; speedup vs baseline: 1.0079x; 1.0079x over previous
//
#include <hip/hip_runtime.h>
#include <cstddef>

#define RR 80
#define NVIEW 4
#define CH 32
#define IH 64
#define IW 64
#define NPIX (IH*IW)
#define NVOX (RR*RR*RR)   // 512000

// G (f16) layout: [v][y][x][g(4)][8] — one pixel = 32 ch = 64 B = 1 cache line.
// b1 is pre-folded into G (bilinear weights sum to 1, so bilerp(G+b1)=bilerp(G)+b1).
#define PIX_H   32              // halves per pixel
#define VIEW_H  (NPIX*PIX_H)    // halves per view

typedef _Float16 half2_t  __attribute__((ext_vector_type(2)));
typedef _Float16 half4_t  __attribute__((ext_vector_type(4)));
typedef _Float16 half8_t  __attribute__((ext_vector_type(8)));
typedef float    float4_t __attribute__((ext_vector_type(4)));

union i2h2 { int i; half2_t h; };

// ---------------------------------------------------------------------------
// G[v][yx][g][e] = b1[8g+e] + sum_ic feats[v][ic][yx] * W1[ic][8g+e]
// 4 threads per pixel (8 out-ch each) -> 256 blocks, 2x the TLP of R2's
// 128-block version (it left half the chip idle on a latency-bound kernel).
// Adjacent tids write consecutive 16B -> perfectly coalesced 64B/pixel.
// ---------------------------------------------------------------------------
__global__ __launch_bounds__(256) void g_precompute(
    const float* __restrict__ feats, const float* __restrict__ W1,
    const float* __restrict__ b1, _Float16* __restrict__ G)
{
    int tid = blockIdx.x*256 + threadIdx.x;      // 0..65535
    int p   = tid >> 2;                          // pixel 0..16383 (v*4096+yx)
    int g   = tid & 3;                           // 8-ch group
    __shared__ float sW1[CH*CH];
    __shared__ float sb1[CH];
    for (int t = threadIdx.x; t < CH*CH; t += 256) sW1[t] = W1[t];
    if (threadIdx.x < CH) sb1[threadIdx.x] = b1[threadIdx.x];
    __syncthreads();
    int v  = p >> 12;
    int yx = p & 4095;
    const float* fb = feats + ((size_t)v*CH)*NPIX + yx;
    float acc[8];
    #pragma unroll
    for (int e=0;e<8;++e) acc[e] = sb1[8*g+e];
    #pragma unroll
    for (int ic=0; ic<CH; ++ic) {
        float fv = fb[(size_t)ic*NPIX];
        #pragma unroll
        for (int e=0;e<8;++e) acc[e] = fmaf(fv, sW1[ic*CH + 8*g + e], acc[e]);
    }
    half8_t h;
    #pragma unroll
    for (int e=0;e<8;++e) h[e] = (_Float16)acc[e];
    *(half8_t*)(G + (size_t)p*PIX_H + (size_t)g*8) = h;
}

// ---------------------------------------------------------------------------
// Main: zero-LDS transposed MFMA MLP, deduplicated projection (64 lanes each
// project their OWN voxel once; packed results redistributed via ds_bpermute).
// R3: reverted R2's explicit depth-2 view pipeline — it pinned 16 half8_t
// (+64 VGPRs) and regressed occupancy for zero latency benefit (kernel is
// issue-bound, R2 measurement). Plain unrolled view loop; compiler schedules
// under a small live set. Keeps pixel-major G and the b1 fold.
// Clamp-based bounds unchanged; invalid lanes get addr 0 and weight 0.
// ---------------------------------------------------------------------------
__global__ __launch_bounds__(256) void dgfv_main(
    const _Float16* __restrict__ G,   // [NVIEW][IH][IW][4][8]
    const float* __restrict__ poses,
    const float* __restrict__ W2, const float* __restrict__ b2,
    const float* __restrict__ W3, const float* __restrict__ b3,
    float* __restrict__ out)
{
    const int wid  = threadIdx.x >> 6;
    const int lane = threadIdx.x & 63;
    const int lq   = lane >> 4;
    const int lc   = lane & 15;
    const int vown  = blockIdx.x*256 + wid*64 + lane;  // producer voxel
    const int vbase = blockIdx.x*256 + wid*64 + lc;    // consumer voxel: vbase+16p

    // ---- wave-resident fragments ----
    half8_t w2a;   // A-frag of W2^T: A[m=lc][k=lq*8+j] = W2[k][m]
    #pragma unroll
    for (int j=0;j<8;++j) w2a[j] = (_Float16)W2[(lq*8+j)*16 + lc];
    half4_t w3a;   // A-frag of W3^T, rows 8..15 duplicate 0..7
    #pragma unroll
    for (int j=0;j<4;++j) w3a[j] = (_Float16)W3[(lq*4+j)*8 + (lc&7)];
    float4_t c1init, c2init;
    #pragma unroll
    for (int r=0;r<4;++r) {
        c1init[r] = b2[lq*4+r];
        c2init[r] = b3[(lq*4+r)&7];
    }

    // ---- producer: project OWN voxel for all views (once, not 4x) ----
    const float step = 2.0f/(float)(RR-1);
    int i  = vown % RR;
    int t  = vown / RR;
    int j_ = t % RR;
    int k_ = t / RR;
    float x = fmaf((float)i,  step, -1.0f);
    float y = fmaf((float)j_, step, -1.0f);
    float z = fmaf((float)k_, step, -1.0f);

    int wpa[NVIEW];   // packed f16 {w00, w10}
    int wpb[NVIEW];   // packed f16 {w01, w11}
    int adm[NVIEW];   // pixel offset in halves | valid<<31  (0 if invalid)
    #pragma unroll
    for (int v=0; v<NVIEW; ++v) {
        const float* P = poses + v*16;           // uniform -> scalar
        float px = fmaf(P[0],x, fmaf(P[1],y, fmaf(P[2], z, P[3])));
        float py = fmaf(P[4],x, fmaf(P[5],y, fmaf(P[6], z, P[7])));
        float pz = fmaf(P[8],x, fmaf(P[9],y, fmaf(P[10],z, P[11])));
        float r0 = __builtin_amdgcn_rcpf(pz);
        r0 = r0*(2.0f - pz*r0);                  // 1 Newton step
        float u  = px*r0;
        float w  = py*r0;

        bool ok = (pz > 0.f) && (u >= 0.f) && (u <= (float)(IW-1))
                             && (w >= 0.f) && (w <= (float)(IH-1));

        float uc = fminf(fmaxf(u, 0.f), (float)(IW-1));
        float wc = fminf(fmaxf(w, 0.f), (float)(IH-1));
        float fx0 = floorf(uc), fy0 = floorf(wc);
        float tx = uc - fx0, ty = wc - fy0;
        int x0 = (int)fx0, y0 = (int)fy0;
        float wx0 = 1.f - tx, wy0 = 1.f - ty;

        i2h2 pa, pb;
        pa.h.x = (_Float16)(wx0*wy0);  pa.h.y = (_Float16)(tx*wy0);
        pb.h.x = (_Float16)(wx0*ty);   pb.h.y = (_Float16)(tx*ty);
        wpa[v] = pa.i;
        wpb[v] = pb.i;
        unsigned paddr = (unsigned)((y0*IW + x0)*PIX_H);
        adm[v] = ok ? (int)(paddr | 0x80000000u) : 0;
    }

    const _Float16* Gq = G + (size_t)lq*8;   // quad's channel-group slice

    #pragma unroll
    for (int p=0; p<4; ++p) {
        const int vx   = vbase + 16*p;
        const int srcb = (lc + 16*p) << 2;   // source lane (bytes) for bpermute

        // redistribute this pass's 16-voxel projection set (addr first so the
        // first gather only waits on the first lgkm group)
        int rm[NVIEW], ra[NVIEW], rb[NVIEW];
        #pragma unroll
        for (int v=0; v<NVIEW; ++v) rm[v] = __builtin_amdgcn_ds_bpermute(srcb, adm[v]);
        #pragma unroll
        for (int v=0; v<NVIEW; ++v) ra[v] = __builtin_amdgcn_ds_bpermute(srcb, wpa[v]);
        #pragma unroll
        for (int v=0; v<NVIEW; ++v) rb[v] = __builtin_amdgcn_ds_bpermute(srcb, wpb[v]);

        float accA[4], accB[4], accM = 0.f;
        #pragma unroll
        for (int r=0;r<4;++r) { accA[r]=0.f; accB[r]=0.f; }

        #pragma unroll
        for (int v=0; v<NVIEW; ++v) {
            i2h2 ua, ub;  ua.i = ra[v];  ub.i = rb[v];
            const bool ok = (rm[v] < 0);          // validity in sign bit
            const int addr = rm[v] & 0x7FFFFFFF;  // pixel offset in halves

            const _Float16* base = Gq + (size_t)v*VIEW_H + addr;
            half8_t a = *(const half8_t*)(base);
            half8_t b = *(const half8_t*)(base + PIX_H);           // x1
            half8_t c = *(const half8_t*)(base + IW*PIX_H);        // y1
            half8_t d = *(const half8_t*)(base + IW*PIX_H + PIX_H);
            half8_t h1 = a*ua.h.x + b*ua.h.y + c*ub.h.x + d*ub.h.y;
            h1 = __builtin_elementwise_max(h1, (half8_t)(_Float16)0.f);

            // layer 2: D1[f2][vox]  (A = W2^T, B = H1^T built in-register)
            float4_t d1 = __builtin_amdgcn_mfma_f32_16x16x32_f16(w2a, h1, c1init, 0,0,0);
            half4_t h2;
            #pragma unroll
            for (int r=0;r<4;++r) h2[r] = (_Float16)fmaxf(d1[r], 0.f);

            // layer 3: D2[fo'][vox]  (relu(D1) C-layout == B-frag for K=16)
            float4_t d2 = __builtin_amdgcn_mfma_f32_16x16x16f16(w3a, h2, c2init, 0,0,0);

            #pragma unroll
            for (int r=0;r<4;++r) {
                float h3 = d2[r];
                float hm = ok ? h3 : 0.f;         // cndmask (mk in {0,1})
                accA[r] += hm;
                accB[r]  = fmaf(hm, h3, accB[r]);
            }
            accM += ok ? 1.f : 0.f;
        }

        // per-pass epilogue: quads 0,1 -> mean, quads 2,3 -> var
        float S   = accM + 1e-8f;
        float inv = 1.f/S;
        float sw  = accM*inv;
        #pragma unroll
        for (int r=0;r<4;++r) {
            float mean = accA[r]*inv;
            float var  = fmaf(-mean*mean, (2.f - sw), accB[r]*inv);
            float val  = (lq < 2) ? mean : var;
            int   cch  = 4*lq + r;
            out[(size_t)cch*NVOX + vx] = val;
        }
    }
}

extern "C" void kernel_launch(void* const* d_in, const int* in_sizes, int n_in,
                              void* d_out, int out_size, void* d_ws, size_t ws_size,
                              hipStream_t stream)
{
    const float* feats = (const float*)d_in[0];
    const float* poses = (const float*)d_in[1];
    const float* W1    = (const float*)d_in[2];
    const float* b1    = (const float*)d_in[3];
    const float* W2    = (const float*)d_in[4];
    const float* b2    = (const float*)d_in[5];
    const float* W3    = (const float*)d_in[6];
    const float* b3    = (const float*)d_in[7];
    float* out = (float*)d_out;

    _Float16* G = (_Float16*)d_ws;   // 1 MB
    g_precompute<<<256, 256, 0, stream>>>(feats, W1, b1, G);
    dgfv_main<<<NVOX/256, 256, 0, stream>>>(G, poses, W2, b2, W3, b3, out);
}

// Round 5
// 99.140 us; speedup vs baseline: 1.0221x; 1.0141x over previous
//
#include <hip/hip_runtime.h>
#include <cstddef>

#define RR 80
#define NVIEW 4
#define CH 32
#define IH 64
#define IW 64
#define NPIX (IH*IW)
#define NVOX (RR*RR*RR)   // 512000

// G (f16) layout: [v][y][x][g(4)][8] — one pixel = 32 ch = 64 B = 1 cache line.
// b1 is pre-folded into G (bilinear weights sum to 1, so bilerp(G+b1)=bilerp(G)+b1).
#define PIX_H   32              // halves per pixel
#define PIX_B   64              // bytes per pixel
#define VIEW_H  (NPIX*PIX_H)    // halves per view
// Byte bias baked into packed offsets so all 4 corner loads land in the
// +-4095 global_load immediate-offset window: offsets become
// {-2080, -2016, +2016, +2080} around base+2080.
#define ADDR_BIAS 2080

typedef _Float16 half2_t  __attribute__((ext_vector_type(2)));
typedef _Float16 half4_t  __attribute__((ext_vector_type(4)));
typedef _Float16 half8_t  __attribute__((ext_vector_type(8)));
typedef float    float4_t __attribute__((ext_vector_type(4)));

union i2h2 { int i; half2_t h; };

// ---------------------------------------------------------------------------
// G[v][yx][g][e] = b1[..] + sum_ic feats[v][ic][yx] * W1[ic][..]
// R4: 512 blocks, 4 out-ch/thread. Lanes cover 64 CONSECUTIVE pixels ->
// each feats load coalesces to 256 B/wave (was 64 B), and 2048 waves give
// 2 waves/SIMD (was 1) for latency hiding on this latency-bound kernel.
// ---------------------------------------------------------------------------
__global__ __launch_bounds__(256) void g_precompute(
    const float* __restrict__ feats, const float* __restrict__ W1,
    const float* __restrict__ b1, _Float16* __restrict__ G)
{
    int g4 = blockIdx.x >> 6;                       // 0..7 (4-ch group)
    int p  = (blockIdx.x & 63)*256 + threadIdx.x;   // pixel 0..16383 (v*4096+yx)
    __shared__ float sW1[CH*4];
    __shared__ float sb1[4];
    if (threadIdx.x < CH*4) {
        int ic = threadIdx.x >> 2, e = threadIdx.x & 3;
        sW1[threadIdx.x] = W1[ic*CH + g4*4 + e];
    }
    if (threadIdx.x < 4) sb1[threadIdx.x] = b1[g4*4 + threadIdx.x];
    __syncthreads();
    int v  = p >> 12;
    int yx = p & 4095;
    const float* fb = feats + ((size_t)v*CH)*NPIX + yx;
    float acc[4];
    #pragma unroll
    for (int e=0;e<4;++e) acc[e] = sb1[e];
    #pragma unroll
    for (int ic=0; ic<CH; ++ic) {
        float fv = fb[(size_t)ic*NPIX];
        #pragma unroll
        for (int e=0;e<4;++e) acc[e] = fmaf(fv, sW1[ic*4+e], acc[e]);
    }
    half4_t h;
    #pragma unroll
    for (int e=0;e<4;++e) h[e] = (_Float16)acc[e];
    *(half4_t*)(G + (size_t)p*PIX_H + g4*4) = h;
}

// ---------------------------------------------------------------------------
// Main: zero-LDS transposed MFMA MLP, deduplicated projection (64 lanes each
// project their OWN voxel once; packed results redistributed via ds_bpermute).
// R4 trims: producer packs the FULL byte offset (incl. view plane + ADDR_BIAS)
// so the consumer does zero address arithmetic beyond the mask; epilogue uses
// hardware rcp (counts are small ints; 1 ulp vs 2^-8 tolerance).
// Clamp-based bounds unchanged; invalid lanes get offset ADDR_BIAS (in-bounds)
// with the valid bit clear.
// ---------------------------------------------------------------------------
__global__ __launch_bounds__(256) void dgfv_main(
    const _Float16* __restrict__ G,   // [NVIEW][IH][IW][4][8]
    const float* __restrict__ poses,
    const float* __restrict__ W2, const float* __restrict__ b2,
    const float* __restrict__ W3, const float* __restrict__ b3,
    float* __restrict__ out)
{
    const int wid  = threadIdx.x >> 6;
    const int lane = threadIdx.x & 63;
    const int lq   = lane >> 4;
    const int lc   = lane & 15;
    const int vown  = blockIdx.x*256 + wid*64 + lane;  // producer voxel
    const int vbase = blockIdx.x*256 + wid*64 + lc;    // consumer voxel: vbase+16p

    // ---- wave-resident fragments ----
    half8_t w2a;   // A-frag of W2^T: A[m=lc][k=lq*8+j] = W2[k][m]
    #pragma unroll
    for (int j=0;j<8;++j) w2a[j] = (_Float16)W2[(lq*8+j)*16 + lc];
    half4_t w3a;   // A-frag of W3^T, rows 8..15 duplicate 0..7
    #pragma unroll
    for (int j=0;j<4;++j) w3a[j] = (_Float16)W3[(lq*4+j)*8 + (lc&7)];
    float4_t c1init, c2init;
    #pragma unroll
    for (int r=0;r<4;++r) {
        c1init[r] = b2[lq*4+r];
        c2init[r] = b3[(lq*4+r)&7];
    }

    // ---- producer: project OWN voxel for all views (once, not 4x) ----
    const float step = 2.0f/(float)(RR-1);
    int i  = vown % RR;
    int t  = vown / RR;
    int j_ = t % RR;
    int k_ = t / RR;
    float x = fmaf((float)i,  step, -1.0f);
    float y = fmaf((float)j_, step, -1.0f);
    float z = fmaf((float)k_, step, -1.0f);

    int wpa[NVIEW];   // packed f16 {w00, w10}
    int wpb[NVIEW];   // packed f16 {w01, w11}
    int adm[NVIEW];   // byte offset (view plane + pixel + ADDR_BIAS) | valid<<31
    #pragma unroll
    for (int v=0; v<NVIEW; ++v) {
        const float* P = poses + v*16;           // uniform -> scalar
        float px = fmaf(P[0],x, fmaf(P[1],y, fmaf(P[2], z, P[3])));
        float py = fmaf(P[4],x, fmaf(P[5],y, fmaf(P[6], z, P[7])));
        float pz = fmaf(P[8],x, fmaf(P[9],y, fmaf(P[10],z, P[11])));
        float r0 = __builtin_amdgcn_rcpf(pz);
        r0 = r0*(2.0f - pz*r0);                  // 1 Newton step
        float u  = px*r0;
        float w  = py*r0;

        bool ok = (pz > 0.f) && (u >= 0.f) && (u <= (float)(IW-1))
                             && (w >= 0.f) && (w <= (float)(IH-1));

        float uc = fminf(fmaxf(u, 0.f), (float)(IW-1));
        float wc = fminf(fmaxf(w, 0.f), (float)(IH-1));
        float fx0 = floorf(uc), fy0 = floorf(wc);
        float tx = uc - fx0, ty = wc - fy0;
        int x0 = (int)fx0, y0 = (int)fy0;
        float wx0 = 1.f - tx, wy0 = 1.f - ty;

        i2h2 pa, pb;
        pa.h.x = (_Float16)(wx0*wy0);  pa.h.y = (_Float16)(tx*wy0);
        pb.h.x = (_Float16)(wx0*ty);   pb.h.y = (_Float16)(tx*ty);
        wpa[v] = pa.i;
        wpb[v] = pb.i;
        unsigned paddr = (unsigned)((v*NPIX + y0*IW + x0)*PIX_B) + ADDR_BIAS;
        adm[v] = ok ? (int)(paddr | 0x80000000u) : (int)ADDR_BIAS;
    }

    const char* Gq = (const char*)(G + (size_t)lq*8);  // quad's channel slice

    #pragma unroll
    for (int p=0; p<4; ++p) {
        const int vx   = vbase + 16*p;
        const int srcb = (lc + 16*p) << 2;   // source lane (bytes) for bpermute

        // redistribute this pass's 16-voxel projection set (addr first so the
        // first gather only waits on the first lgkm group)
        int rm[NVIEW], ra[NVIEW], rb[NVIEW];
        #pragma unroll
        for (int v=0; v<NVIEW; ++v) rm[v] = __builtin_amdgcn_ds_bpermute(srcb, adm[v]);
        #pragma unroll
        for (int v=0; v<NVIEW; ++v) ra[v] = __builtin_amdgcn_ds_bpermute(srcb, wpa[v]);
        #pragma unroll
        for (int v=0; v<NVIEW; ++v) rb[v] = __builtin_amdgcn_ds_bpermute(srcb, wpb[v]);

        float accA[4], accB[4], accM = 0.f;
        #pragma unroll
        for (int r=0;r<4;++r) { accA[r]=0.f; accB[r]=0.f; }

        #pragma unroll
        for (int v=0; v<NVIEW; ++v) {
            i2h2 ua, ub;  ua.i = ra[v];  ub.i = rb[v];
            const bool ok = (rm[v] < 0);          // validity in sign bit

            const char* basep = Gq + (rm[v] & 0x7FFFFFFF);
            half8_t a = *(const half8_t*)(basep - ADDR_BIAS);
            half8_t b = *(const half8_t*)(basep - ADDR_BIAS + PIX_B);       // x1
            half8_t c = *(const half8_t*)(basep - ADDR_BIAS + IW*PIX_B);    // y1
            half8_t d = *(const half8_t*)(basep - ADDR_BIAS + IW*PIX_B + PIX_B);
            half8_t h1 = a*ua.h.x + b*ua.h.y + c*ub.h.x + d*ub.h.y;
            h1 = __builtin_elementwise_max(h1, (half8_t)(_Float16)0.f);

            // layer 2: D1[f2][vox]  (A = W2^T, B = H1^T built in-register)
            float4_t d1 = __builtin_amdgcn_mfma_f32_16x16x32_f16(w2a, h1, c1init, 0,0,0);
            half4_t h2;
            #pragma unroll
            for (int r=0;r<4;++r) h2[r] = (_Float16)fmaxf(d1[r], 0.f);

            // layer 3: D2[fo'][vox]  (relu(D1) C-layout == B-frag for K=16)
            float4_t d2 = __builtin_amdgcn_mfma_f32_16x16x16f16(w3a, h2, c2init, 0,0,0);

            #pragma unroll
            for (int r=0;r<4;++r) {
                float h3 = d2[r];
                float hm = ok ? h3 : 0.f;         // cndmask (mk in {0,1})
                accA[r] += hm;
                accB[r]  = fmaf(hm, h3, accB[r]);
            }
            accM += ok ? 1.f : 0.f;
        }

        // per-pass epilogue: quads 0,1 -> mean, quads 2,3 -> var
        float inv = __builtin_amdgcn_rcpf(accM + 1e-8f);  // counts are small ints
        float sw  = accM*inv;
        #pragma unroll
        for (int r=0;r<4;++r) {
            float mean = accA[r]*inv;
            float var  = fmaf(-mean*mean, (2.f - sw), accB[r]*inv);
            float val  = (lq < 2) ? mean : var;
            int   cch  = 4*lq + r;
            out[(size_t)cch*NVOX + vx] = val;
        }
    }
}

extern "C" void kernel_launch(void* const* d_in, const int* in_sizes, int n_in,
                              void* d_out, int out_size, void* d_ws, size_t ws_size,
                              hipStream_t stream)
{
    const float* feats = (const float*)d_in[0];
    const float* poses = (const float*)d_in[1];
    const float* W1    = (const float*)d_in[2];
    const float* b1    = (const float*)d_in[3];
    const float* W2    = (const float*)d_in[4];
    const float* b2    = (const float*)d_in[5];
    const float* W3    = (const float*)d_in[6];
    const float* b3    = (const float*)d_in[7];
    float* out = (float*)d_out;

    _Float16* G = (_Float16*)d_ws;   // 1 MB
    g_precompute<<<512, 256, 0, stream>>>(feats, W1, b1, G);
    dgfv_main<<<NVOX/256, 256, 0, stream>>>(G, poses, W2, b2, W3, b3, out);
}